// Round 4
// baseline (322.048 us; speedup 1.0000x reference)
//
#include <hip/hip_runtime.h>
#include <math.h>

#define NPATH 70656
#define NBATCH 512
#define OUTD 480
#define OUTSZ (OUTD*OUTD)   // 230400 per point
#define ZCH 128             // z-chunk per block (w2 re-read = 512/ZCH = 4x = 72 MB)

// c-region start offset per pair p = lo*3+li
// sizes: 16384,8192,4096 | 8192,12288,6144 | 4096,6144,5120
constexpr int CBEG_TAB[9] = {0,16384,24576,28672,36864,49152,55296,59392,65536};

struct QPtrs { const float* q[9]; };

// ---------------- Kernel A: spherical harmonics + h (z-major) ----------------
__global__ __launch_bounds__(256) void sh_mlp_kernel(
    const float* __restrict__ r, const float* __restrict__ w1,
    const float* __restrict__ b1, float* __restrict__ Yg,
    float* __restrict__ hTz)
{
  int z = blockIdx.x*256 + threadIdx.x;
  if (z >= NBATCH) return;
  float x = r[3*z], y = r[3*z+1], zz = r[3*z+2];
  float nrm = sqrtf(x*x + y*y + zz*zz);
  float inv = 1.0f / fmaxf(nrm, 1e-9f);
  float dx = x*inv, dy = y*inv, dz = zz*inv;
  float rxy = sqrtf(fmaxf(dx*dx + dy*dy, 1e-18f));
  float cphi = dx/rxy, sphi = dy/rxy;
  float somx2 = sqrtf(fmaxf(1.0f - dz*dz, 1e-12f));

  float P[5][5];
  float pmm = 1.0f;
  #pragma unroll
  for (int m = 0; m < 5; ++m) {
    if (m > 0) pmm *= (float)(2*m-1) * somx2;
    P[m][m] = pmm;
    if (m+1 < 5) P[m+1][m] = dz * (float)(2*m+1) * pmm;
    #pragma unroll
    for (int l = m+2; l < 5; ++l)
      P[l][m] = ((float)(2*l-1)*dz*P[l-1][m] - (float)(l+m-1)*P[l-2][m]) / (float)(l-m);
  }
  float cm[5], sm[5];
  cm[0]=1.0f; sm[0]=0.0f; cm[1]=cphi; sm[1]=sphi;
  #pragma unroll
  for (int m = 2; m < 5; ++m) {
    cm[m] = cm[m-1]*cphi - sm[m-1]*sphi;
    sm[m] = sm[m-1]*cphi + cm[m-1]*sphi;
  }
  const float fact[9] = {1,1,2,6,24,120,720,5040,40320};
  int row = 0;
  #pragma unroll
  for (int l = 0; l < 5; ++l) {
    #pragma unroll
    for (int m = -l; m <= l; ++m) {
      int am = m < 0 ? -m : m;
      float N = sqrtf((float)(2*l+1) / 12.566370614359172f * fact[l-am] / fact[l+am]);
      float v;
      if (m == 0)      v = N * P[l][0];
      else if (m > 0)  v = 1.4142135623730951f * N * P[l][am] * cm[am];
      else             v = 1.4142135623730951f * N * P[l][am] * sm[am];
      Yg[z*25 + row] = v;
      ++row;
    }
  }
  #pragma unroll
  for (int k = 0; k < 64; ++k)
    hTz[z*64 + k] = fmaxf(nrm * w1[k] + b1[k], 0.0f);
}

// ---------------- Fused coefficient + tensor-product body ----------------
// Block = up to 256 paths of one region x one z-chunk. w2 in VGPRs (reused
// over 128 z), h via wave-uniform s_load, c -> LDS, A from LDS Y-slice,
// all output addressing hoisted out of the z-loop. 1 barrier/z (dbuf LDS).
template<int LO, int LI>
__device__ __forceinline__ void region_body(
    int bidl, const float* __restrict__ Yg, const float* __restrict__ hTz,
    const float* __restrict__ w2f, const float* __restrict__ b2,
    const float* __restrict__ Q, float* __restrict__ out,
    float* Ysl, float* c_lds, float* A_lds)
{
  constexpr int DI = 2*LO+1, DJ = 2*LI+1;
  constexpr int MO = 128>>LO, MI = 128>>LI;
  constexpr int NL = 2*((LO<LI)?LO:LI)+1;
  constexpr int LF0 = (LO>LI)?(LO-LI):(LI-LO);
  constexpr int QDIM = (LO+LI+1)*(LO+LI+1) - LF0*LF0;
  constexpr int NUV = MO*MI;
  constexpr int G = 256/NL;                 // uv-pairs per block
  constexpr int UVB = (NUV + G - 1)/G;      // uv-blocks per chunk
  constexpr int NOUT = G*DI*DJ;             // outputs per block per z
  constexpr int OPT = (NOUT + 255)/256;     // outputs per thread
  constexpr int ASIZE = DI*DJ*NL;           // <= 125
  constexpr int MAXM = 2*(LO+LI)+1;         // widest filter
  constexpr int ROWOFF = (LO==0)?0:((LO==1)?128:320);
  constexpr int COLOFF = (LI==0)?0:((LI==1)?128:320);
  constexpr int CBEG = CBEG_TAB[LO*3+LI];
  constexpr float NS = (LO==0)?224.0f:((LO==1)?416.0f:480.0f);
  const float xn = sqrtf((float)(2*LI+1) * 12.566370614359172f / NS);

  const int tid = threadIdx.x;
  const int uvb   = bidl % UVB;
  const int chunk = bidl / UVB;
  const int uv0 = uvb * G;
  const int z0  = chunk * ZCH;

  // ---- c-phase setup: this thread's path, w2 column in VGPRs ----
  const int gl = (NL==1) ? tid : (tid / NL);
  const int kf = (NL==1) ? 0   : (tid % NL);
  const bool cact = (gl < G) && (uv0 + gl < NUV);
  const int path = CBEG + (cact ? ((uv0+gl)*NL + kf) : 0);
  float w2c[64];
  #pragma unroll
  for (int k = 0; k < 64; ++k) w2c[k] = w2f[(size_t)k*NPATH + path];
  const float b2p = b2[path];

  // ---- A-phase setup: Q values are z-invariant -> VGPRs ----
  float Qv[MAXM];
  int yb = 0;
  {
    int t = (tid < ASIZE) ? tid : 0;
    int i  = t / (DJ*NL);
    int j  = (t / NL) % DJ;
    int kA = t % NL;
    int lf = LF0 + kA;
    int qoff = kA*(2*LF0 + kA);
    int mlim = 2*lf + 1;
    yb = lf*lf;
    #pragma unroll
    for (int m = 0; m < MAXM; ++m)
      Qv[m] = (m < mlim) ? Q[(i*DJ + j)*QDIM + qoff + m] : 0.0f;
  }

  // ---- output setup: addressing hoisted out of the z-loop ----
  int rowoff_o[OPT], aidx_o[OPT], cidx_o[OPT];
  bool val_o[OPT];
  #pragma unroll
  for (int t = 0; t < OPT; ++t) {
    int o = tid + 256*t;
    bool v = o < NOUT;
    int oo = v ? o : 0;
    int i   = oo / (G*DJ);
    int rem = oo % (G*DJ);
    int g   = rem / DJ;
    int j   = rem % DJ;
    int uv  = uv0 + g;
    v = v && (uv < NUV);
    int uu = uv >> (7-LI);          // / MI (pow2)
    int vv = uv & (MI-1);
    rowoff_o[t] = (uu*DI + i)*OUTD + vv*DJ + j;
    aidx_o[t] = (i*DJ + j)*NL;
    cidx_o[t] = g*NL;
    val_o[t] = v;
  }

  // ---- stage Y slice for this z-chunk (contiguous, coalesced) ----
  for (int idx = tid; idx < ZCH*25; idx += 256) Ysl[idx] = Yg[z0*25 + idx];
  __syncthreads();

  float* outR = out + ROWOFF*OUTD + COLOFF;

  for (int zr = 0; zr < ZCH; ++zr) {
    const int z = __builtin_amdgcn_readfirstlane(z0 + zr);
    const float* hz = hTz + (size_t)z*64;          // wave-uniform -> s_load
    float c0 = b2p, c1 = 0.0f, c2 = 0.0f, c3 = 0.0f;
    #pragma unroll
    for (int k = 0; k < 64; k += 4) {
      c0 = fmaf(hz[k],   w2c[k],   c0);
      c1 = fmaf(hz[k+1], w2c[k+1], c1);
      c2 = fmaf(hz[k+2], w2c[k+2], c2);
      c3 = fmaf(hz[k+3], w2c[k+3], c3);
    }
    float* cb = c_lds + (zr & 1)*256;
    float* ab = A_lds + (zr & 1)*128;
    cb[tid] = (c0 + c1) + (c2 + c3);
    if (tid < ASIZE) {
      const float* yz = Ysl + zr*25 + yb;
      float s = 0.0f;
      #pragma unroll
      for (int m = 0; m < MAXM; ++m) s = fmaf(Qv[m], yz[m], s);
      ab[tid] = s;
    }
    __syncthreads();   // dbuf: one barrier per z is sufficient
    float* oz = outR + (size_t)z*OUTSZ;
    #pragma unroll
    for (int t = 0; t < OPT; ++t) {
      if (val_o[t]) {
        float s = 0.0f;
        #pragma unroll
        for (int k = 0; k < NL; ++k) s += ab[aidx_o[t] + k] * cb[cidx_o[t] + k];
        oz[rowoff_o[t]] = s*xn;
      }
    }
  }
}

// block-count prefix per region (UVB x 4 chunks):
// UVB = {64,32,16,32,49,25,16,25,21} -> x4 = {256,128,64,128,196,100,64,100,84}
__global__ __launch_bounds__(256) void tp_fused_kernel(
    const float* __restrict__ Yg, const float* __restrict__ hTz,
    const float* __restrict__ w2, const float* __restrict__ b2,
    QPtrs qp, float* __restrict__ out)
{
  __shared__ float Ysl[ZCH*25];   // 12.8 KB
  __shared__ float c_lds[512];    // double-buffered
  __shared__ float A_lds[256];    // double-buffered
  const int b = blockIdx.x;
  if      (b <  256) region_body<0,0>(b,       Yg,hTz,w2,b2,qp.q[0],out,Ysl,c_lds,A_lds);
  else if (b <  384) region_body<0,1>(b- 256,  Yg,hTz,w2,b2,qp.q[1],out,Ysl,c_lds,A_lds);
  else if (b <  448) region_body<0,2>(b- 384,  Yg,hTz,w2,b2,qp.q[2],out,Ysl,c_lds,A_lds);
  else if (b <  576) region_body<1,0>(b- 448,  Yg,hTz,w2,b2,qp.q[3],out,Ysl,c_lds,A_lds);
  else if (b <  772) region_body<1,1>(b- 576,  Yg,hTz,w2,b2,qp.q[4],out,Ysl,c_lds,A_lds);
  else if (b <  872) region_body<1,2>(b- 772,  Yg,hTz,w2,b2,qp.q[5],out,Ysl,c_lds,A_lds);
  else if (b <  936) region_body<2,0>(b- 872,  Yg,hTz,w2,b2,qp.q[6],out,Ysl,c_lds,A_lds);
  else if (b < 1036) region_body<2,1>(b- 936,  Yg,hTz,w2,b2,qp.q[7],out,Ysl,c_lds,A_lds);
  else               region_body<2,2>(b-1036,  Yg,hTz,w2,b2,qp.q[8],out,Ysl,c_lds,A_lds);
}

extern "C" void kernel_launch(void* const* d_in, const int* in_sizes, int n_in,
                              void* d_out, int out_size, void* d_ws, size_t ws_size,
                              hipStream_t stream)
{
  (void)in_sizes; (void)n_in; (void)out_size; (void)ws_size;
  const float* r  = (const float*)d_in[0];
  const float* w1 = (const float*)d_in[1];
  const float* b1 = (const float*)d_in[2];
  const float* w2 = (const float*)d_in[3];
  const float* b2 = (const float*)d_in[4];
  float* out = (float*)d_out;

  float* ws  = (float*)d_ws;
  float* Yg  = ws;             // 512*25 = 12800 floats
  float* hTz = ws + 12800;     // 512*64 = 32768 floats

  QPtrs qp;
  for (int i = 0; i < 9; ++i) qp.q[i] = (const float*)d_in[5 + i];

  hipLaunchKernelGGL(sh_mlp_kernel, dim3(2), dim3(256), 0, stream, r, w1, b1, Yg, hTz);
  hipLaunchKernelGGL(tp_fused_kernel, dim3(1120), dim3(256), 0, stream,
                     Yg, hTz, w2, b2, qp, out);
}

// Round 5
// 219.858 us; speedup vs baseline: 1.4648x; 1.4648x over previous
//
#include <hip/hip_runtime.h>
#include <math.h>

#define NPATH 70656
#define NBATCH 512
#define OUTD 480
#define OUTSZ (OUTD*OUTD)   // 230400 per point
#define ZCHV 64             // z-chunk per block
#define ZT 8                // z-tile (barrier / store-drain granularity)

// c-region start offset per pair p = lo*3+li
// sizes: 16384,8192,4096 | 8192,12288,6144 | 4096,6144,5120
constexpr int CBEG_TAB[9] = {0,16384,24576,28672,36864,49152,55296,59392,65536};

struct QPtrs { const float* q[9]; };

// ---------------- Kernel A: spherical harmonics + h (z-major) ----------------
__global__ __launch_bounds__(256) void sh_mlp_kernel(
    const float* __restrict__ r, const float* __restrict__ w1,
    const float* __restrict__ b1, float* __restrict__ Yg,
    float* __restrict__ hTz)
{
  int z = blockIdx.x*256 + threadIdx.x;
  if (z >= NBATCH) return;
  float x = r[3*z], y = r[3*z+1], zz = r[3*z+2];
  float nrm = sqrtf(x*x + y*y + zz*zz);
  float inv = 1.0f / fmaxf(nrm, 1e-9f);
  float dx = x*inv, dy = y*inv, dz = zz*inv;
  float rxy = sqrtf(fmaxf(dx*dx + dy*dy, 1e-18f));
  float cphi = dx/rxy, sphi = dy/rxy;
  float somx2 = sqrtf(fmaxf(1.0f - dz*dz, 1e-12f));

  float P[5][5];
  float pmm = 1.0f;
  #pragma unroll
  for (int m = 0; m < 5; ++m) {
    if (m > 0) pmm *= (float)(2*m-1) * somx2;
    P[m][m] = pmm;
    if (m+1 < 5) P[m+1][m] = dz * (float)(2*m+1) * pmm;
    #pragma unroll
    for (int l = m+2; l < 5; ++l)
      P[l][m] = ((float)(2*l-1)*dz*P[l-1][m] - (float)(l+m-1)*P[l-2][m]) / (float)(l-m);
  }
  float cm[5], sm[5];
  cm[0]=1.0f; sm[0]=0.0f; cm[1]=cphi; sm[1]=sphi;
  #pragma unroll
  for (int m = 2; m < 5; ++m) {
    cm[m] = cm[m-1]*cphi - sm[m-1]*sphi;
    sm[m] = sm[m-1]*cphi + cm[m-1]*sphi;
  }
  const float fact[9] = {1,1,2,6,24,120,720,5040,40320};
  int row = 0;
  #pragma unroll
  for (int l = 0; l < 5; ++l) {
    #pragma unroll
    for (int m = -l; m <= l; ++m) {
      int am = m < 0 ? -m : m;
      float N = sqrtf((float)(2*l+1) / 12.566370614359172f * fact[l-am] / fact[l+am]);
      float v;
      if (m == 0)      v = N * P[l][0];
      else if (m > 0)  v = 1.4142135623730951f * N * P[l][am] * cm[am];
      else             v = 1.4142135623730951f * N * P[l][am] * sm[am];
      Yg[z*25 + row] = v;
      ++row;
    }
  }
  #pragma unroll
  for (int k = 0; k < 64; ++k)
    hTz[z*64 + k] = fmaxf(nrm * w1[k] + b1[k], 0.0f);
}

// ---------------- Streaming body: NL==1 regions (LO==0 || LI==0) ------------
// path == uv, so c stays in registers: no LDS, NO barriers, pure store stream.
// A is wave-uniform (scalar-loaded Y, Q) and cheap to recompute per thread.
// w2 loads kk-chunked (16 at a time over an 8-z register tile) so the per-z
// dependent-load chain from R4 (VGPR=56 proved w2c was rematerialized) is gone.
template<int LO, int LI>
__device__ __forceinline__ void stream_body(
    int bidl, const float* __restrict__ Yg, const float* __restrict__ hTz,
    const float* __restrict__ w2f, const float* __restrict__ b2,
    const float* __restrict__ Q, float* __restrict__ out)
{
  constexpr int DI = 2*LO+1, DJ = 2*LI+1;
  constexpr int MI = 128>>LI;
  constexpr int NUV = (128>>LO)*MI;
  constexpr int UVB = NUV/256;               // NUV % 256 == 0 for all 5 regions
  constexpr int LF = LO+LI;                  // the single filter l
  constexpr int MAXM = 2*LF+1;               // == QDIM here
  constexpr int ROWOFF = (LO==0)?0:((LO==1)?128:320);
  constexpr int COLOFF = (LI==0)?0:((LI==1)?128:320);
  constexpr int CBEG = CBEG_TAB[LO*3+LI];
  constexpr float NS = (LO==0)?224.0f:((LO==1)?416.0f:480.0f);
  const float xn = sqrtf((float)(2*LI+1) * 12.566370614359172f / NS);

  const int tid = threadIdx.x;
  const int uvb   = bidl % UVB;
  const int chunk = bidl / UVB;
  const int z0 = chunk * ZCHV;
  const int uv = uvb*256 + tid;
  const int uu = uv >> (7-LI);               // uv / MI
  const int vv = uv & (MI-1);
  const int path = CBEG + uv;
  const float b2p = b2[path];

  float Qv[DI*DJ][MAXM];                     // thread-invariant
  #pragma unroll
  for (int ij = 0; ij < DI*DJ; ++ij)
    #pragma unroll
    for (int m = 0; m < MAXM; ++m)
      Qv[ij][m] = Q[ij*MAXM + m];

  float* outR = out + (size_t)(ROWOFF + uu*DI)*OUTD + COLOFF + vv*DJ;

  for (int t0 = 0; t0 < ZCHV; t0 += ZT) {
    float acc[ZT];
    #pragma unroll
    for (int zt = 0; zt < ZT; ++zt) acc[zt] = b2p;
    #pragma unroll
    for (int kk = 0; kk < 64; kk += 16) {
      float w2c[16];
      #pragma unroll
      for (int k = 0; k < 16; ++k) w2c[k] = w2f[(size_t)(kk+k)*NPATH + path];
      #pragma unroll
      for (int zt = 0; zt < ZT; ++zt) {
        const float* hz = hTz + (size_t)(z0+t0+zt)*64 + kk;   // wave-uniform
        float s0=0.f, s1=0.f, s2=0.f, s3=0.f;
        #pragma unroll
        for (int k = 0; k < 16; k += 4) {
          s0 = fmaf(hz[k],   w2c[k],   s0);
          s1 = fmaf(hz[k+1], w2c[k+1], s1);
          s2 = fmaf(hz[k+2], w2c[k+2], s2);
          s3 = fmaf(hz[k+3], w2c[k+3], s3);
        }
        acc[zt] += (s0+s1)+(s2+s3);
      }
    }
    #pragma unroll
    for (int zt = 0; zt < ZT; ++zt) {
      const int z = z0 + t0 + zt;
      const float* yz = Yg + (size_t)z*25 + LF*LF;            // wave-uniform
      const float c = acc[zt]*xn;
      float* oz = outR + (size_t)z*OUTSZ;
      #pragma unroll
      for (int i = 0; i < DI; ++i)
        #pragma unroll
        for (int j = 0; j < DJ; ++j) {
          float a = 0.0f;
          #pragma unroll
          for (int m = 0; m < MAXM; ++m) a = fmaf(Qv[i*DJ+j][m], yz[m], a);
          oz[i*OUTD + j] = a*c;
        }
    }
  }
}

// ---------------- Tiled body: NL>1 regions ----------------------------------
// thread=path, c exchanged via LDS but computed for an 8-z tile per barrier
// (parity double-buffer -> exactly ONE barrier / 8 z; store drains amortized).
template<int LO, int LI>
__device__ __forceinline__ void tiled_body(
    int bidl, const float* __restrict__ Yg, const float* __restrict__ hTz,
    const float* __restrict__ w2f, const float* __restrict__ b2,
    const float* __restrict__ Q, float* __restrict__ out,
    float* c_lds, float* A_lds)
{
  constexpr int DI = 2*LO+1, DJ = 2*LI+1;
  constexpr int MO = 128>>LO, MI = 128>>LI;
  constexpr int NL = 2*((LO<LI)?LO:LI)+1;
  constexpr int LF0 = (LO>LI)?(LO-LI):(LI-LO);
  constexpr int QDIM = (LO+LI+1)*(LO+LI+1) - LF0*LF0;
  constexpr int NUV = MO*MI;
  constexpr int G = 256/NL;
  constexpr int UVB = (NUV + G - 1)/G;
  constexpr int NOUT = G*DI*DJ;
  constexpr int OPT = (NOUT + 255)/256;
  constexpr int ASIZE = DI*DJ*NL;            // <= 125
  constexpr int MAXM = 2*(LO+LI)+1;
  constexpr int ROWOFF = (LO==0)?0:((LO==1)?128:320);
  constexpr int COLOFF = (LI==0)?0:((LI==1)?128:320);
  constexpr int CBEG = CBEG_TAB[LO*3+LI];
  constexpr float NS = (LO==0)?224.0f:((LO==1)?416.0f:480.0f);
  const float xn = sqrtf((float)(2*LI+1) * 12.566370614359172f / NS);

  const int tid = threadIdx.x;
  const int uvb   = bidl % UVB;
  const int chunk = bidl / UVB;
  const int uv0 = uvb * G;
  const int z0  = chunk * ZCHV;

  const int gl = tid / NL;
  const int kf = tid % NL;
  const bool cact = (gl < G) && (uv0 + gl < NUV);
  const int path = CBEG + (cact ? ((uv0+gl)*NL + kf) : 0);
  const float b2p = b2[path];

  // A-phase setup: Q values z-invariant -> registers
  float Qv[MAXM];
  int yb = 0;
  {
    int t = (tid < ASIZE) ? tid : 0;
    int i  = t / (DJ*NL);
    int j  = (t / NL) % DJ;
    int kA = t % NL;
    int lf = LF0 + kA;
    int qoff = kA*(2*LF0 + kA);
    int mlim = 2*lf + 1;
    yb = lf*lf;
    #pragma unroll
    for (int m = 0; m < MAXM; ++m)
      Qv[m] = (m < mlim) ? Q[(i*DJ + j)*QDIM + qoff + m] : 0.0f;
  }

  // output addressing hoisted out of all z loops
  int rowoff_o[OPT], aidx_o[OPT], cidx_o[OPT];
  bool val_o[OPT];
  #pragma unroll
  for (int t = 0; t < OPT; ++t) {
    int o = tid + 256*t;
    bool v = o < NOUT;
    int oo = v ? o : 0;
    int i   = oo / (G*DJ);
    int rem = oo % (G*DJ);
    int g   = rem / DJ;
    int j   = rem % DJ;
    int uv  = uv0 + g;
    v = v && (uv < NUV);
    int uu = uv >> (7-LI);
    int vv = uv & (MI-1);
    rowoff_o[t] = (uu*DI + i)*OUTD + vv*DJ + j;
    aidx_o[t] = (i*DJ + j)*NL;
    cidx_o[t] = g*NL;
    val_o[t] = v;
  }

  float* outR = out + ROWOFF*OUTD + COLOFF;

  for (int tile = 0; tile < ZCHV/ZT; ++tile) {
    const int p = tile & 1;
    float* cb = c_lds + p*(ZT*256);
    float* ab = A_lds + p*(ZT*128);
    const int zb = z0 + tile*ZT;

    // ---- c-phase: kk-chunked w2 (16 loads amortized over 8 z) ----
    float acc[ZT];
    #pragma unroll
    for (int zt = 0; zt < ZT; ++zt) acc[zt] = b2p;
    #pragma unroll
    for (int kk = 0; kk < 64; kk += 16) {
      float w2c[16];
      #pragma unroll
      for (int k = 0; k < 16; ++k) w2c[k] = w2f[(size_t)(kk+k)*NPATH + path];
      #pragma unroll
      for (int zt = 0; zt < ZT; ++zt) {
        const float* hz = hTz + (size_t)(zb+zt)*64 + kk;      // wave-uniform
        float s0=0.f, s1=0.f, s2=0.f, s3=0.f;
        #pragma unroll
        for (int k = 0; k < 16; k += 4) {
          s0 = fmaf(hz[k],   w2c[k],   s0);
          s1 = fmaf(hz[k+1], w2c[k+1], s1);
          s2 = fmaf(hz[k+2], w2c[k+2], s2);
          s3 = fmaf(hz[k+3], w2c[k+3], s3);
        }
        acc[zt] += (s0+s1)+(s2+s3);
      }
    }
    #pragma unroll
    for (int zt = 0; zt < ZT; ++zt) cb[zt*256 + tid] = acc[zt];

    // ---- A-phase ----
    if (tid < ASIZE) {
      #pragma unroll
      for (int zt = 0; zt < ZT; ++zt) {
        const float* yz = Yg + (size_t)(zb+zt)*25 + yb;
        float s = 0.0f;
        #pragma unroll
        for (int m = 0; m < MAXM; ++m) s = fmaf(Qv[m], yz[m], s);
        ab[zt*128 + tid] = s;
      }
    }
    __syncthreads();   // one barrier per 8 z (parity dbuf makes trailing barrier unnecessary)

    // ---- out-phase: 8 z of stores, no syncs ----
    for (int zt = 0; zt < ZT; ++zt) {
      float* oz = outR + (size_t)(zb+zt)*OUTSZ;
      const float* cbz = cb + zt*256;
      const float* abz = ab + zt*128;
      #pragma unroll
      for (int t = 0; t < OPT; ++t) {
        if (val_o[t]) {
          float s = 0.0f;
          #pragma unroll
          for (int k = 0; k < NL; ++k) s += abz[aidx_o[t] + k] * cbz[cidx_o[t] + k];
          oz[rowoff_o[t]] = s*xn;
        }
      }
    }
  }
}

// stream regions per chunk: (0,0)x64 (0,1)x32 (0,2)x16 (1,0)x32 (2,0)x16 = 160
__global__ __launch_bounds__(256) void tp_stream_kernel(
    const float* __restrict__ Yg, const float* __restrict__ hTz,
    const float* __restrict__ w2, const float* __restrict__ b2,
    QPtrs qp, float* __restrict__ out)
{
  const int b = blockIdx.x;
  const int chunk = b / 160;
  const int r = b % 160;
  if      (r <  64) stream_body<0,0>(chunk*64 + r,      Yg,hTz,w2,b2,qp.q[0],out);
  else if (r <  96) stream_body<0,1>(chunk*32 + (r- 64),Yg,hTz,w2,b2,qp.q[1],out);
  else if (r < 112) stream_body<0,2>(chunk*16 + (r- 96),Yg,hTz,w2,b2,qp.q[2],out);
  else if (r < 144) stream_body<1,0>(chunk*32 + (r-112),Yg,hTz,w2,b2,qp.q[3],out);
  else              stream_body<2,0>(chunk*16 + (r-144),Yg,hTz,w2,b2,qp.q[6],out);
}

// tiled regions per chunk: (1,1)x49 (1,2)x25 (2,1)x25 (2,2)x21 = 120
__global__ __launch_bounds__(256) void tp_tiled_kernel(
    const float* __restrict__ Yg, const float* __restrict__ hTz,
    const float* __restrict__ w2, const float* __restrict__ b2,
    QPtrs qp, float* __restrict__ out)
{
  __shared__ float c_lds[2*ZT*256];   // 16 KB
  __shared__ float A_lds[2*ZT*128];   // 8 KB
  const int b = blockIdx.x;
  const int chunk = b / 120;
  const int r = b % 120;
  if      (r <  49) tiled_body<1,1>(chunk*49 + r,      Yg,hTz,w2,b2,qp.q[4],out,c_lds,A_lds);
  else if (r <  74) tiled_body<1,2>(chunk*25 + (r-49), Yg,hTz,w2,b2,qp.q[5],out,c_lds,A_lds);
  else if (r <  99) tiled_body<2,1>(chunk*25 + (r-74), Yg,hTz,w2,b2,qp.q[7],out,c_lds,A_lds);
  else              tiled_body<2,2>(chunk*21 + (r-99), Yg,hTz,w2,b2,qp.q[8],out,c_lds,A_lds);
}

extern "C" void kernel_launch(void* const* d_in, const int* in_sizes, int n_in,
                              void* d_out, int out_size, void* d_ws, size_t ws_size,
                              hipStream_t stream)
{
  (void)in_sizes; (void)n_in; (void)out_size; (void)ws_size;
  const float* r  = (const float*)d_in[0];
  const float* w1 = (const float*)d_in[1];
  const float* b1 = (const float*)d_in[2];
  const float* w2 = (const float*)d_in[3];
  const float* b2 = (const float*)d_in[4];
  float* out = (float*)d_out;

  float* ws  = (float*)d_ws;
  float* Yg  = ws;             // 512*25 = 12800 floats
  float* hTz = ws + 12800;     // 512*64 = 32768 floats

  QPtrs qp;
  for (int i = 0; i < 9; ++i) qp.q[i] = (const float*)d_in[5 + i];

  const int nchunk = NBATCH / ZCHV;   // 8
  hipLaunchKernelGGL(sh_mlp_kernel, dim3(2), dim3(256), 0, stream, r, w1, b1, Yg, hTz);
  hipLaunchKernelGGL(tp_tiled_kernel,  dim3(nchunk*120), dim3(256), 0, stream,
                     Yg, hTz, w2, b2, qp, out);
  hipLaunchKernelGGL(tp_stream_kernel, dim3(nchunk*160), dim3(256), 0, stream,
                     Yg, hTz, w2, b2, qp, out);
}